// Round 8
// baseline (217.406 us; speedup 1.0000x reference)
//
#include <hip/hip_runtime.h>
#include <hip/hip_fp16.h>

typedef int      v4i __attribute__((ext_vector_type(4)));
typedef int      v2i __attribute__((ext_vector_type(2)));
typedef float    v4f __attribute__((ext_vector_type(4)));
typedef _Float16 v8h __attribute__((ext_vector_type(8)));
typedef _Float16 v4h __attribute__((ext_vector_type(4)));

#define MDIM 8192
#define NDIM 4096
#define KDIM 4096
#define RDIM 64
#define KW   (KDIM / 2)
#define NT   (KDIM / 64)         // 64 K-tiles of 64 int8 (one mfma K each)

typedef const __attribute__((address_space(1))) char* gas_ptr;
typedef __attribute__((address_space(3))) char*       las_ptr;

__device__ __forceinline__ void unpack_w(v4i w, int& lo8, int& hi8) {
    unsigned p01 = __builtin_amdgcn_perm((unsigned)w.y, (unsigned)w.x, 0x0C0C0400u);
    unsigned p23 = __builtin_amdgcn_perm((unsigned)w.w, (unsigned)w.z, 0x0C0C0400u);
    unsigned b4  = __builtin_amdgcn_perm(p23, p01, 0x05040100u);
    unsigned lo = b4 & 0x0F0F0F0Fu;
    unsigned hi = (b4 >> 4) & 0x0F0F0F0Fu;
    lo8 = (int)(((lo ^ 0x08080808u) + 0x78787878u) ^ 0x80808080u);
    hi8 = (int)(((hi ^ 0x08080808u) + 0x78787878u) ^ 0x80808080u);
}

// ---- kernel 1: repack. x -> linear int8 rows; w -> [n/16][k/16][16][16] ----
// B tiling makes a 16x16B fragment load fully contiguous (1KB/wave from L2).
__global__ __launch_bounds__(256)
void repack_int4(const int* __restrict__ xq, const int* __restrict__ wq,
                 char* __restrict__ x8, char* __restrict__ w8t)
{
    const size_t XCH = (size_t)MDIM * KW / 4;              // 4-word chunks
    const size_t TCH = XCH + (size_t)NDIM * KW / 4;
    size_t stride = (size_t)gridDim.x * blockDim.x;
    for (size_t i = (size_t)blockIdx.x * blockDim.x + threadIdx.x; i < TCH; i += stride) {
        v4i w;
        char* dst;
        if (i < XCH) {
            w = *(const v4i*)(xq + i * 4);
            dst = x8 + i * 8;                              // linear
        } else {
            size_t j = i - XCH;
            w = *(const v4i*)(wq + j * 4);
            int n  = (int)(j >> 9);                        // 512 chunks per row
            int kc = (int)(j & 511);                       // 8-byte k-run index
            size_t off = (size_t)(n >> 4) * 65536 + (size_t)(kc >> 1) * 256
                       + (n & 15) * 16 + (kc & 1) * 8;
            dst = w8t + off;
        }
        int lo8, hi8;
        unpack_w(w, lo8, hi8);
        *(v2i*)dst = (v2i){lo8, hi8};
    }
}

// ---- kernel 2: 128x128 int8 GEMM, A via LDS (depth-4), B via L2->regs -----
__device__ __forceinline__ void stageA(const char* g, char* l, int kt) {
    const char* s = g + kt * 64;
    __builtin_amdgcn_global_load_lds((gas_ptr)(const void*)s,
                                     (las_ptr)(void*)l, 16, 0, 0);
    __builtin_amdgcn_global_load_lds((gas_ptr)(const void*)(s + (size_t)16 * KDIM),
                                     (las_ptr)(void*)(l + 1024), 16, 0, 0);
}

#define BAR asm volatile("s_barrier" ::: "memory")
#define VM2 asm volatile("s_waitcnt vmcnt(2)" ::: "memory")

#define READ_A4(dst, BASE)                                                     \
    _Pragma("unroll")                                                          \
    for (int ii = 0; ii < 4; ++ii)                                             \
        dst[ii] = *(const v4i*)((BASE) + aoff + ii * 1024)

#define LOADB(dst, KT)                                                         \
    _Pragma("unroll")                                                          \
    for (int jj = 0; jj < 4; ++jj)                                             \
        dst[jj] = *(const v4i*)(gBbase + (size_t)(KT) * 1024 + jj * 65536)

#define MMA16(AS, BS)                                                          \
    __builtin_amdgcn_s_setprio(1);                                             \
    _Pragma("unroll")                                                          \
    for (int ii = 0; ii < 4; ++ii)                                             \
        _Pragma("unroll")                                                      \
        for (int jj = 0; jj < 4; ++jj)                                         \
            acc[ii][jj] = __builtin_amdgcn_mfma_i32_16x16x64_i8(               \
                AS[ii], BS[jj], acc[ii][jj], 0, 0, 0);                         \
    __builtin_amdgcn_s_setprio(0)

// phase kt: read A frags (slot kt&3), prefetch B(kt+1)->BF, stage A(kt+2),
// MFMA on BU (prefetched last phase), vmcnt(2) certifies {A,B}(kt+1), barrier.
#define PHASE(KT, BU, BF) do {                                                 \
    const int kt_ = (KT);                                                      \
    READ_A4(fa, &Asl[kt_ & 3][0]);                                             \
    const int ktb = (kt_ + 1 < NT) ? kt_ + 1 : NT - 1;                         \
    LOADB(BF, ktb);                                                            \
    const int kta = (kt_ + 2 < NT) ? kt_ + 2 : NT - 1;                         \
    stageA(gA, &Asl[(kt_ + 2) & 3][ldsW], kta);                                \
    MMA16(fa, BU);                                                             \
    VM2; BAR;                                                                  \
} while (0)

__global__ __launch_bounds__(256, 3)
void w4a4_split(const char* __restrict__ x8, const char* __restrict__ w8t,
                const float* __restrict__ xsc, const float* __restrict__ wsc,
                const float* __restrict__ bias, const float* __restrict__ xr,
                const float* __restrict__ wo, float* __restrict__ out)
{
    // A: 4 kt-slots x [128 rows x 64B], swizzled: byte c of row r holds
    // global col c ^ (((r>>1)&3)<<4). 32 KiB -> 3 blocks/CU.
    __shared__ __align__(16) char Asl[4][8192];
    __shared__ float xs_s[128];
    __shared__ float ws_s[128];
    __shared__ float bs_s[128];

    const int tid  = threadIdx.x;
    const int lane = tid & 63;
    const int wid  = tid >> 6;     // 0..3
    const int wm   = wid >> 1;     // M half (0..1)
    const int wn   = wid & 1;      // N half (0..1)

    // XCD-grouped swizzle: XCD x owns 4 B column-panels (L2-resident).
    const int xcd = blockIdx.x & 7;
    const int idx = blockIdx.x >> 3;          // 0..255
    const int bxn = xcd * 4 + (idx >> 6);     // 0..31
    const int by  = idx & 63;                 // 0..63

    if (tid < 128) {
        xs_s[tid] = xsc[by * 128 + tid];
    } else {
        int n = tid - 128;
        ws_s[n] = wsc[bxn * 128 + n];
        bs_s[n] = bias[bxn * 128 + n];
    }

    // A staging: wave covers rows wid*32 + (lane>>2) (+16 on 2nd issue)
    const int scol = ((lane & 3) * 16) ^ (((lane >> 3) & 3) << 4);
    const int srow = wid * 32 + (lane >> 2);
    const char* gA = x8 + (size_t)(by * 128 + srow) * KDIM + scol;
    const int ldsW = wid * 2048;

    // B addressing into the tiled layout: frag col = bxn*128+wn*64+jj*16+lr
    const int lr = lane & 15;
    const char* gBbase = w8t + (size_t)(bxn * 8 + wn * 4) * 65536
                       + lr * 16 + (lane >> 4) * 256;

    // A fragment read geometry (swizzle XOR is lane-constant)
    const int cef  = ((lane >> 4) << 4) ^ (((lr >> 1) & 3) << 4);
    const int aoff = (wm * 64 + lr) * 64 + cef;

    v4i acc[4][4];
#pragma unroll
    for (int i = 0; i < 4; ++i)
#pragma unroll
        for (int j = 0; j < 4; ++j) acc[i][j] = (v4i){0, 0, 0, 0};

    v4i fa[4], bA[4], bB[4];

    // prologue queue: [A0 2][B0 4][A1 2]; vmcnt(2) drains A0,B0.
    stageA(gA, &Asl[0][ldsW], 0);
    LOADB(bA, 0);
    stageA(gA, &Asl[1][ldsW], 1);
    VM2; BAR;

    // Ledger (6 vm-events/phase/wave: B 4 then A 2): end of phase kt the
    // queue is [A(kt+1) 2][B(kt+1) 4][A(kt+2) 2]; vmcnt(2) drains the first
    // six -> next phase's A slot and B regs certified. Tail stages/loads
    // clamp to NT-1 and target only never-read slots (kt+2 wraps past NT).
    for (int kt = 0; kt < NT; kt += 2) {
        PHASE(kt,     bA, bB);
        PHASE(kt + 1, bB, bA);
    }

    // drain DMAs before overwriting LDS with the f16 outlier tiles
    asm volatile("s_waitcnt vmcnt(0)" ::: "memory");
    BAR;

    // ---- rank-64 outlier staging: f16 [128][64] (128B rows), XOR-swizzled
    // byte ^= ((row&7)<<4). Xh = Asl[0..1], Wh = Asl[2..3] (16K each).
    char* Xh = (char*)&Asl[0][0];
    char* Wh = (char*)&Asl[2][0];
    {
        const int rr = tid >> 3;          // 0..31
        const int cb = (tid & 7) * 16;    // byte col within 128B row
#pragma unroll
        for (int p = 0; p < 4; ++p) {
            const int row = p * 32 + rr;
            const int sw = cb ^ ((row & 7) << 4);
            v4f x0 = *(const v4f*)(xr + (size_t)(by * 128 + row) * RDIM + (cb >> 1));
            v4f x1 = *(const v4f*)(xr + (size_t)(by * 128 + row) * RDIM + (cb >> 1) + 4);
            v8h hx = {(_Float16)x0[0], (_Float16)x0[1], (_Float16)x0[2], (_Float16)x0[3],
                      (_Float16)x1[0], (_Float16)x1[1], (_Float16)x1[2], (_Float16)x1[3]};
            *(v8h*)(Xh + (size_t)row * 128 + sw) = hx;
            v4f w0 = *(const v4f*)(wo + (size_t)(bxn * 128 + row) * RDIM + (cb >> 1));
            v4f w1 = *(const v4f*)(wo + (size_t)(bxn * 128 + row) * RDIM + (cb >> 1) + 4);
            v8h hw = {(_Float16)w0[0], (_Float16)w0[1], (_Float16)w0[2], (_Float16)w0[3],
                      (_Float16)w1[0], (_Float16)w1[1], (_Float16)w1[2], (_Float16)w1[3]};
            *(v8h*)(Wh + (size_t)row * 128 + sw) = hw;
        }
    }

    // dequant in place (int acc -> f32 bits), overlaps the LDS staging above
#pragma unroll
    for (int i = 0; i < 4; ++i) {
        const int r0 = wm * 64 + i * 16 + ((lane >> 4) << 2);
        const v4f xs4 = *(const v4f*)&xs_s[r0];
#pragma unroll
        for (int j = 0; j < 4; ++j) {
            const int col = wn * 64 + j * 16 + lr;
            const float sw = ws_s[col];
            const float bz = bs_s[col];
            v4f f;
#pragma unroll
            for (int r = 0; r < 4; ++r)
                f[r] = (float)acc[i][j][r] * xs4[r] * sw + bz;
            acc[i][j] = __builtin_bit_cast(v4i, f);
        }
    }
    __syncthreads();

    // rank-64 outlier, f16 MFMA accumulating into the dequantized f32 frags
#pragma unroll
    for (int ks = 0; ks < 2; ++ks) {
        v8h ah[4], bh[4];
#pragma unroll
        for (int i = 0; i < 4; ++i) {
            const int row = wm * 64 + i * 16 + lr;
            const int c   = (ks * 64 + ((lane >> 4) << 4)) ^ ((row & 7) << 4);
            ah[i] = *(const v8h*)(Xh + (size_t)row * 128 + c);
        }
#pragma unroll
        for (int j = 0; j < 4; ++j) {
            const int row = wn * 64 + j * 16 + lr;
            const int c   = (ks * 64 + ((lane >> 4) << 4)) ^ ((row & 7) << 4);
            bh[j] = *(const v8h*)(Wh + (size_t)row * 128 + c);
        }
#pragma unroll
        for (int i = 0; i < 4; ++i)
#pragma unroll
            for (int j = 0; j < 4; ++j) {
                v4f c = __builtin_bit_cast(v4f, acc[i][j]);
                c = __builtin_amdgcn_mfma_f32_16x16x32_f16(ah[i], bh[j], c, 0, 0, 0);
                acc[i][j] = __builtin_bit_cast(v4i, c);
            }
    }

    const size_t obase = (size_t)(by * 128 + wm * 64 + ((lane >> 4) << 2)) * NDIM
                       + bxn * 128 + wn * 64 + lr;
#pragma unroll
    for (int i = 0; i < 4; ++i)
#pragma unroll
        for (int j = 0; j < 4; ++j) {
            v4f f = __builtin_bit_cast(v4f, acc[i][j]);
#pragma unroll
            for (int r = 0; r < 4; ++r)
                out[obase + (size_t)(i * 16 + r) * NDIM + j * 16] = f[r];
        }
}

// ---------------- fallback: fused single-kernel path (ws too small) --------
__global__ __launch_bounds__(256, 2)
void w4a4_fused(const int* __restrict__ xq, const float* __restrict__ xsc,
                const int* __restrict__ wq, const float* __restrict__ wsc,
                const float* __restrict__ bias, const float* __restrict__ xr,
                const float* __restrict__ wo, float* __restrict__ out)
{
    __shared__ __align__(16) char As[128 * 144];
    __shared__ __align__(16) char Bs[128 * 144];
    __shared__ float xs_s[128];
    __shared__ float ws_s[128];
    __shared__ float bs_s[128];

    const int tid  = threadIdx.x;
    const int lane = tid & 63;
    const int wid  = tid >> 6;
    const int wm   = wid >> 1;
    const int wn   = wid & 1;
    const int bx   = blockIdx.x % (NDIM / 128);
    const int by   = blockIdx.x / (NDIM / 128);

    const int srow   = tid >> 4;
    const int schunk = tid & 15;

    if (tid < 128) {
        xs_s[tid] = xsc[by * 128 + tid];
    } else {
        int n = tid - 128;
        ws_s[n] = wsc[bx * 128 + n];
        bs_s[n] = bias[bx * 128 + n];
    }

    const int* gA = xq + (size_t)(by * 128 + srow) * KW + schunk * 4;
    const int* gB = wq + (size_t)(bx * 128 + srow) * KW + schunk * 4;
    char* lA = As + srow * 144 + schunk * 8;
    char* lB = Bs + srow * 144 + schunk * 8;

    v4i acc[4][4];
#pragma unroll
    for (int i = 0; i < 4; ++i)
#pragma unroll
        for (int j = 0; j < 4; ++j) acc[i][j] = (v4i){0, 0, 0, 0};

    const int lr = lane & 15;
    const int lkb = (lane >> 4) * 16;

    for (int kt = 0; kt < KDIM / 128; ++kt) {
#pragma unroll
        for (int p = 0; p < 8; ++p) {
            v4i w = *(const v4i*)(gA + (size_t)p * 16 * KW + kt * 64);
            int lo8, hi8;
            unpack_w(w, lo8, hi8);
            *(v2i*)(lA + p * 16 * 144) = (v2i){lo8, hi8};
        }
#pragma unroll
        for (int p = 0; p < 8; ++p) {
            v4i w = *(const v4i*)(gB + (size_t)p * 16 * KW + kt * 64);
            int lo8, hi8;
            unpack_w(w, lo8, hi8);
            *(v2i*)(lB + p * 16 * 144) = (v2i){lo8, hi8};
        }
        __syncthreads();
#pragma unroll
        for (int ks = 0; ks < 2; ++ks) {
            v4i av[4], bv[4];
#pragma unroll
            for (int i = 0; i < 4; ++i)
                av[i] = *(const v4i*)(As + (wm * 64 + i * 16 + lr) * 144 + ks * 64 + lkb);
#pragma unroll
            for (int j = 0; j < 4; ++j)
                bv[j] = *(const v4i*)(Bs + (wn * 64 + j * 16 + lr) * 144 + ks * 64 + lkb);
#pragma unroll
            for (int i = 0; i < 4; ++i)
#pragma unroll
                for (int j = 0; j < 4; ++j)
                    acc[i][j] = __builtin_amdgcn_mfma_i32_16x16x64_i8(av[i], bv[j], acc[i][j], 0, 0, 0);
        }
        __syncthreads();
    }

    _Float16* Xh = (_Float16*)As;
    _Float16* Wh = (_Float16*)Bs;
#pragma unroll
    for (int p = 0; p < 8; ++p) {
        int row = p * 16 + srow;
        float4 vx = *(const float4*)(xr + (size_t)(by * 128 + row) * RDIM + schunk * 4);
        *(v4h*)(Xh + row * 72 + schunk * 4) =
            (v4h){(_Float16)vx.x, (_Float16)vx.y, (_Float16)vx.z, (_Float16)vx.w};
        float4 vw = *(const float4*)(wo + (size_t)(bx * 128 + row) * RDIM + schunk * 4);
        *(v4h*)(Wh + row * 72 + schunk * 4) =
            (v4h){(_Float16)vw.x, (_Float16)vw.y, (_Float16)vw.z, (_Float16)vw.w};
    }
    __syncthreads();

    v4f facc[4][4];
#pragma unroll
    for (int i = 0; i < 4; ++i)
#pragma unroll
        for (int j = 0; j < 4; ++j) facc[i][j] = (v4f){0.f, 0.f, 0.f, 0.f};

    const int lkh = (lane >> 4) * 8;
#pragma unroll
    for (int ks = 0; ks < 2; ++ks) {
        v8h ah[4], bh[4];
#pragma unroll
        for (int i = 0; i < 4; ++i)
            ah[i] = *(const v8h*)(Xh + (wm * 64 + i * 16 + lr) * 72 + ks * 32 + lkh);
#pragma unroll
        for (int j = 0; j < 4; ++j)
            bh[j] = *(const v8h*)(Wh + (wn * 64 + j * 16 + lr) * 72 + ks * 32 + lkh);
#pragma unroll
        for (int i = 0; i < 4; ++i)
#pragma unroll
            for (int j = 0; j < 4; ++j)
                facc[i][j] = __builtin_amdgcn_mfma_f32_16x16x32_f16(ah[i], bh[j], facc[i][j], 0, 0, 0);
    }

#pragma unroll
    for (int i = 0; i < 4; ++i) {
        int row0 = wm * 64 + i * 16 + (lane >> 4) * 4;
#pragma unroll
        for (int j = 0; j < 4; ++j) {
            int col = wn * 64 + j * 16 + lr;
            float sw = ws_s[col];
            float bz = bs_s[col];
#pragma unroll
            for (int r = 0; r < 4; ++r) {
                int row = row0 + r;
                float v = (float)acc[i][j][r] * xs_s[row] * sw + bz + facc[i][j][r];
                out[(size_t)(by * 128 + row) * NDIM + (bx * 128 + col)] = v;
            }
        }
    }
}

extern "C" void kernel_launch(void* const* d_in, const int* in_sizes, int n_in,
                              void* d_out, int out_size, void* d_ws, size_t ws_size,
                              hipStream_t stream) {
    const int*   xq   = (const int*)d_in[0];
    const float* xsc  = (const float*)d_in[1];
    const int*   wq   = (const int*)d_in[2];
    const float* wsc  = (const float*)d_in[3];
    const float* bias = (const float*)d_in[4];
    const float* xr   = (const float*)d_in[5];
    const float* wo   = (const float*)d_in[6];
    float* out = (float*)d_out;

    const size_t X8 = (size_t)MDIM * KDIM;   // 32 MiB
    const size_t W8 = (size_t)NDIM * KDIM;   // 16 MiB (tiled)

    if (ws_size >= X8 + W8) {
        char* x8  = (char*)d_ws;
        char* w8t = x8 + X8;
        repack_int4<<<2048, 256, 0, stream>>>(xq, wq, x8, w8t);
        w4a4_split<<<(MDIM / 128) * (NDIM / 128), 256, 0, stream>>>(
            x8, w8t, xsc, wsc, bias, xr, wo, out);
    } else {
        w4a4_fused<<<(MDIM / 128) * (NDIM / 128), 256, 0, stream>>>(
            xq, xsc, wq, wsc, bias, xr, wo, out);
    }
}

// Round 9
// 203.792 us; speedup vs baseline: 1.0668x; 1.0668x over previous
//
#include <hip/hip_runtime.h>
#include <hip/hip_fp16.h>

typedef int      v4i __attribute__((ext_vector_type(4)));
typedef int      v2i __attribute__((ext_vector_type(2)));
typedef float    v4f __attribute__((ext_vector_type(4)));
typedef _Float16 v8h __attribute__((ext_vector_type(8)));
typedef _Float16 v4h __attribute__((ext_vector_type(4)));

#define MDIM 8192
#define NDIM 4096
#define KDIM 4096
#define RDIM 64
#define KW   (KDIM / 2)
#define NHALF (KDIM / 64)        // 64 K-steps of 64 int8

typedef const __attribute__((address_space(1))) char* gas_ptr;
typedef __attribute__((address_space(3))) char*       las_ptr;

__device__ __forceinline__ void unpack_w(v4i w, int& lo8, int& hi8) {
    unsigned p01 = __builtin_amdgcn_perm((unsigned)w.y, (unsigned)w.x, 0x0C0C0400u);
    unsigned p23 = __builtin_amdgcn_perm((unsigned)w.w, (unsigned)w.z, 0x0C0C0400u);
    unsigned b4  = __builtin_amdgcn_perm(p23, p01, 0x05040100u);
    unsigned lo = b4 & 0x0F0F0F0Fu;
    unsigned hi = (b4 >> 4) & 0x0F0F0F0Fu;
    lo8 = (int)(((lo ^ 0x08080808u) + 0x78787878u) ^ 0x80808080u);
    hi8 = (int)(((hi ^ 0x08080808u) + 0x78787878u) ^ 0x80808080u);
}

// ---------------- kernel 1: repack packed-int32 nibbles -> dense int8 -------
__global__ __launch_bounds__(256)
void repack_int4(const int* __restrict__ xq, const int* __restrict__ wq,
                 char* __restrict__ x8, char* __restrict__ w8)
{
    const size_t XCH = (size_t)MDIM * KW / 4;
    const size_t TCH = XCH + (size_t)NDIM * KW / 4;
    size_t stride = (size_t)gridDim.x * blockDim.x;
    for (size_t i = (size_t)blockIdx.x * blockDim.x + threadIdx.x; i < TCH; i += stride) {
        const int* src;
        char* dst;
        if (i < XCH) { src = xq + i * 4; dst = x8 + i * 8; }
        else { size_t j = i - XCH; src = wq + j * 4; dst = w8 + j * 8; }
        v4i w = *(const v4i*)src;
        int lo8, hi8;
        unpack_w(w, lo8, hi8);
        *(v2i*)dst = (v2i){lo8, hi8};
    }
}

// ---- kernel 2: 256x256 block, 4 waves, wave tile 128x128, acc[8][8] -------
// Big-tile / low-occupancy config (Tensile-style): LDS feed per FLOP drops
// 33% vs 8-wave 128x64; full 512-reg budget at 1 wave/SIMD holds the 256-reg
// accumulator plus double-buffered fragment sets (no spill by construction).
__device__ __forceinline__ void stage_half(const char* g, char* l, int hh) {
#pragma unroll
    for (int q = 0; q < 4; ++q)
        __builtin_amdgcn_global_load_lds(
            (gas_ptr)(const void*)(g + (size_t)(q * 64) * KDIM + hh * 64),
            (las_ptr)(void*)(l + q * 4096), 16, 0, 0);
}

#define BAR   asm volatile("s_barrier" ::: "memory")
#define VM0   asm volatile("s_waitcnt vmcnt(0)" ::: "memory")
#define LGKM0 do { asm volatile("s_waitcnt lgkmcnt(0)" ::: "memory");          \
                   __builtin_amdgcn_sched_barrier(0); } while (0)
#define SGB(m, n) __builtin_amdgcn_sched_group_barrier(m, n, 0)

// weave: 8 VMEM (stages) into first 16 MFMA, 16 DS_READ into remaining 48
#define SGBWEAVE do {                                                          \
    _Pragma("unroll")                                                          \
    for (int s_ = 0; s_ < 8; ++s_) { SGB(0x30, 1); SGB(0x8, 2); }              \
    _Pragma("unroll")                                                          \
    for (int s_ = 0; s_ < 8; ++s_) { SGB(0x100, 2); SGB(0x8, 6); }             \
} while (0)

#define READ8(dst, BASE, OFF)                                                  \
    _Pragma("unroll")                                                          \
    for (int ii = 0; ii < 8; ++ii)                                             \
        dst[ii] = *(const v4i*)((BASE) + (OFF) + ii * 1024)

#define MMA64(AS, BS)                                                          \
    _Pragma("unroll")                                                          \
    for (int ii = 0; ii < 8; ++ii)                                             \
        _Pragma("unroll")                                                      \
        for (int jj = 0; jj < 8; ++jj)                                         \
            acc[ii][jj] = __builtin_amdgcn_mfma_i32_16x16x64_i8(               \
                AS[ii], BS[jj], acc[ii][jj], 0, 0, 0)

// phase: VM0 (prior stage certified) -> stage h+2 -> read next frags ->
// 64 MFMA on cur frags (SGB-woven) -> lgkm0 (WAR fence) -> barrier
#define PHASE(CURA, CURB, NXTA, NXTB, RBUFA, RBUFB, SBUFA, SBUFB, HS) do {     \
    VM0;                                                                       \
    stage_half(gA, SBUFA, HS);                                                 \
    stage_half(gB, SBUFB, HS);                                                 \
    READ8(NXTA, RBUFA, aoff);                                                  \
    READ8(NXTB, RBUFB, boff);                                                  \
    MMA64(CURA, CURB);                                                         \
    SGBWEAVE;                                                                  \
    LGKM0;                                                                     \
    BAR;                                                                       \
} while (0)

__global__ __launch_bounds__(256, 1)
void w4a4_big(const char* __restrict__ x8, const char* __restrict__ w8,
              const float* __restrict__ xsc, const float* __restrict__ wsc,
              const float* __restrict__ bias, const float* __restrict__ xr,
              const float* __restrict__ wo, float* __restrict__ out)
{
    // [parity][256 rows x 64B], swizzled: byte c of row r holds global col
    // c ^ (((r>>1)&3)<<4). 64 KiB tiles + 3 KiB scales.
    __shared__ __align__(16) char Abuf[2][16384];
    __shared__ __align__(16) char Bbuf[2][16384];
    __shared__ float xs_s[256];
    __shared__ float ws_s[256];
    __shared__ float bs_s[256];

    const int tid  = threadIdx.x;
    const int lane = tid & 63;
    const int wid  = tid >> 6;     // 0..3
    const int wm   = wid >> 1;     // M half (0..1)
    const int wn   = wid & 1;      // N half (0..1)

    // bijective XCD swizzle: 512 blocks = 8 XCDs x 64
    const int s  = (blockIdx.x & 7) * 64 + (blockIdx.x >> 3);
    const int by = s >> 4;         // 0..31
    const int bxn = s & 15;        // 0..15

    xs_s[tid] = xsc[by * 256 + tid];
    ws_s[tid] = wsc[bxn * 256 + tid];
    bs_s[tid] = bias[bxn * 256 + tid];

    // staging geometry: wave covers rows {q*64 + wid*16 + lane/4}, 16B/lane,
    // source col pre-swizzled (lane-constant XOR)
    const int scol = ((lane & 3) * 16) ^ (((lane >> 3) & 3) << 4);
    const int srow = wid * 16 + (lane >> 2);
    const char* gA = x8 + (size_t)(by * 256 + srow) * KDIM + scol;
    const char* gB = w8 + (size_t)(bxn * 256 + srow) * KDIM + scol;
    const int ldsW = wid * 1024;

    // fragment read geometry (swizzle XOR is lane-constant)
    const int lr   = lane & 15;
    const int cef  = ((lane >> 4) << 4) ^ (((lr >> 1) & 3) << 4);
    const int aoff = (wm * 128 + lr) * 64 + cef;
    const int boff = (wn * 128 + lr) * 64 + cef;

    v4i acc[8][8];
#pragma unroll
    for (int i = 0; i < 8; ++i)
#pragma unroll
        for (int j = 0; j < 8; ++j) acc[i][j] = (v4i){0, 0, 0, 0};

    // prologue: half0 -> buf0, half1 -> buf1; drain all; read half0 frags.
    stage_half(gA, &Abuf[0][ldsW], 0);
    stage_half(gB, &Bbuf[0][ldsW], 0);
    stage_half(gA, &Abuf[1][ldsW], 1);
    stage_half(gB, &Bbuf[1][ldsW], 1);
    VM0; BAR;

    v4i fa0[8], fb0[8], fa1[8], fb1[8];
    READ8(fa0, (const char*)&Abuf[0][0], aoff);
    READ8(fb0, (const char*)&Bbuf[0][0], boff);
    LGKM0;      // my reads of buf0 done before anyone stages into it at h=0
    BAR;

    // Rotation (verified h=0..3 + tail): even phase h computes half h (fa0),
    // reads half h+1 from buf1 into fa1, stages half h+2 into buf0. VM0 at
    // phase top drains the stage issued last phase (depth-1 > HBM latency).
    // Tail clamps re-stage half 63 into dead-but-harmless slots.
    for (int h = 0; h < NHALF; h += 2) {
        const int hs0 = (h + 2 < NHALF) ? h + 2 : NHALF - 1;
        const int hs1 = (h + 3 < NHALF) ? h + 3 : NHALF - 1;
        PHASE(fa0, fb0, fa1, fb1,
              (const char*)&Abuf[1][0], (const char*)&Bbuf[1][0],
              &Abuf[0][ldsW], &Bbuf[0][ldsW], hs0);
        PHASE(fa1, fb1, fa0, fb0,
              (const char*)&Abuf[0][0], (const char*)&Bbuf[0][0],
              &Abuf[1][ldsW], &Bbuf[1][ldsW], hs1);
    }

    // drain DMAs before overwriting LDS with the f16 outlier tiles
    VM0; BAR;

    // ---- rank-64 outlier staging: f16 [256][64] (128B rows), XOR-swizzled
    // byte ^= ((row&7)<<4). Xh reuses Abuf (32K), Wh reuses Bbuf.
    char* Xh = (char*)&Abuf[0][0];
    char* Wh = (char*)&Bbuf[0][0];
    {
        const int rr = tid >> 3;          // 0..31
        const int cb = (tid & 7) * 16;    // byte col within 128B row
#pragma unroll
        for (int p = 0; p < 8; ++p) {
            const int row = p * 32 + rr;
            const int sw = cb ^ ((row & 7) << 4);
            v4f x0 = *(const v4f*)(xr + (size_t)(by * 256 + row) * RDIM + (cb >> 1));
            v4f x1 = *(const v4f*)(xr + (size_t)(by * 256 + row) * RDIM + (cb >> 1) + 4);
            v8h hx = {(_Float16)x0[0], (_Float16)x0[1], (_Float16)x0[2], (_Float16)x0[3],
                      (_Float16)x1[0], (_Float16)x1[1], (_Float16)x1[2], (_Float16)x1[3]};
            *(v8h*)(Xh + (size_t)row * 128 + sw) = hx;
            v4f w0 = *(const v4f*)(wo + (size_t)(bxn * 256 + row) * RDIM + (cb >> 1));
            v4f w1 = *(const v4f*)(wo + (size_t)(bxn * 256 + row) * RDIM + (cb >> 1) + 4);
            v8h hw = {(_Float16)w0[0], (_Float16)w0[1], (_Float16)w0[2], (_Float16)w0[3],
                      (_Float16)w1[0], (_Float16)w1[1], (_Float16)w1[2], (_Float16)w1[3]};
            *(v8h*)(Wh + (size_t)row * 128 + sw) = hw;
        }
    }

    // dequant in place (int acc -> f32 bits), overlaps the LDS staging above
#pragma unroll
    for (int i = 0; i < 8; ++i) {
        const int r0 = wm * 128 + i * 16 + ((lane >> 4) << 2);
        const v4f xs4 = *(const v4f*)&xs_s[r0];
#pragma unroll
        for (int j = 0; j < 8; ++j) {
            const int col = wn * 128 + j * 16 + lr;
            const float sw = ws_s[col];
            const float bz = bs_s[col];
            v4f f;
#pragma unroll
            for (int r = 0; r < 4; ++r)
                f[r] = (float)acc[i][j][r] * xs4[r] * sw + bz;
            acc[i][j] = __builtin_bit_cast(v4i, f);
        }
    }
    __syncthreads();

    // rank-64 outlier, f16 MFMA accumulating into the dequantized f32 frags
#pragma unroll
    for (int ks = 0; ks < 2; ++ks) {
        v8h ah[8], bh[8];
#pragma unroll
        for (int i = 0; i < 8; ++i) {
            const int row = wm * 128 + i * 16 + lr;
            const int c   = (ks * 64 + ((lane >> 4) << 4)) ^ ((row & 7) << 4);
            ah[i] = *(const v8h*)(Xh + (size_t)row * 128 + c);
        }
#pragma unroll
        for (int j = 0; j < 8; ++j) {
            const int row = wn * 128 + j * 16 + lr;
            const int c   = (ks * 64 + ((lane >> 4) << 4)) ^ ((row & 7) << 4);
            bh[j] = *(const v8h*)(Wh + (size_t)row * 128 + c);
        }
#pragma unroll
        for (int i = 0; i < 8; ++i)
#pragma unroll
            for (int j = 0; j < 8; ++j) {
                v4f c = __builtin_bit_cast(v4f, acc[i][j]);
                c = __builtin_amdgcn_mfma_f32_16x16x32_f16(ah[i], bh[j], c, 0, 0, 0);
                acc[i][j] = __builtin_bit_cast(v4i, c);
            }
    }

    const size_t obase = (size_t)(by * 256 + wm * 128 + ((lane >> 4) << 2)) * NDIM
                       + bxn * 256 + wn * 128 + lr;
#pragma unroll
    for (int i = 0; i < 8; ++i)
#pragma unroll
        for (int j = 0; j < 8; ++j) {
            v4f f = __builtin_bit_cast(v4f, acc[i][j]);
#pragma unroll
            for (int r = 0; r < 4; ++r)
                out[obase + (size_t)(i * 16 + r) * NDIM + j * 16] = f[r];
        }
}

// ---------------- fallback: fused single-kernel path (ws too small) --------
__global__ __launch_bounds__(256, 2)
void w4a4_fused(const int* __restrict__ xq, const float* __restrict__ xsc,
                const int* __restrict__ wq, const float* __restrict__ wsc,
                const float* __restrict__ bias, const float* __restrict__ xr,
                const float* __restrict__ wo, float* __restrict__ out)
{
    __shared__ __align__(16) char As[128 * 144];
    __shared__ __align__(16) char Bs[128 * 144];
    __shared__ float xs_s[128];
    __shared__ float ws_s[128];
    __shared__ float bs_s[128];

    const int tid  = threadIdx.x;
    const int lane = tid & 63;
    const int wid  = tid >> 6;
    const int wm   = wid >> 1;
    const int wn   = wid & 1;
    const int bx   = blockIdx.x % (NDIM / 128);
    const int by   = blockIdx.x / (NDIM / 128);

    const int srow   = tid >> 4;
    const int schunk = tid & 15;

    if (tid < 128) {
        xs_s[tid] = xsc[by * 128 + tid];
    } else {
        int n = tid - 128;
        ws_s[n] = wsc[bx * 128 + n];
        bs_s[n] = bias[bx * 128 + n];
    }

    const int* gA = xq + (size_t)(by * 128 + srow) * KW + schunk * 4;
    const int* gB = wq + (size_t)(bx * 128 + srow) * KW + schunk * 4;
    char* lA = As + srow * 144 + schunk * 8;
    char* lB = Bs + srow * 144 + schunk * 8;

    v4i acc[4][4];
#pragma unroll
    for (int i = 0; i < 4; ++i)
#pragma unroll
        for (int j = 0; j < 4; ++j) acc[i][j] = (v4i){0, 0, 0, 0};

    const int lr = lane & 15;
    const int lkb = (lane >> 4) * 16;

    for (int kt = 0; kt < KDIM / 128; ++kt) {
#pragma unroll
        for (int p = 0; p < 8; ++p) {
            v4i w = *(const v4i*)(gA + (size_t)p * 16 * KW + kt * 64);
            int lo8, hi8;
            unpack_w(w, lo8, hi8);
            *(v2i*)(lA + p * 16 * 144) = (v2i){lo8, hi8};
        }
#pragma unroll
        for (int p = 0; p < 8; ++p) {
            v4i w = *(const v4i*)(gB + (size_t)p * 16 * KW + kt * 64);
            int lo8, hi8;
            unpack_w(w, lo8, hi8);
            *(v2i*)(lB + p * 16 * 144) = (v2i){lo8, hi8};
        }
        __syncthreads();
#pragma unroll
        for (int ks = 0; ks < 2; ++ks) {
            v4i av[4], bv[4];
#pragma unroll
            for (int i = 0; i < 4; ++i)
                av[i] = *(const v4i*)(As + (wm * 64 + i * 16 + lr) * 144 + ks * 64 + lkb);
#pragma unroll
            for (int j = 0; j < 4; ++j)
                bv[j] = *(const v4i*)(Bs + (wn * 64 + j * 16 + lr) * 144 + ks * 64 + lkb);
#pragma unroll
            for (int i = 0; i < 4; ++i)
#pragma unroll
                for (int j = 0; j < 4; ++j)
                    acc[i][j] = __builtin_amdgcn_mfma_i32_16x16x64_i8(av[i], bv[j], acc[i][j], 0, 0, 0);
        }
        __syncthreads();
    }

    _Float16* Xh = (_Float16*)As;
    _Float16* Wh = (_Float16*)Bs;
#pragma unroll
    for (int p = 0; p < 8; ++p) {
        int row = p * 16 + srow;
        float4 vx = *(const float4*)(xr + (size_t)(by * 128 + row) * RDIM + schunk * 4);
        *(v4h*)(Xh + row * 72 + schunk * 4) =
            (v4h){(_Float16)vx.x, (_Float16)vx.y, (_Float16)vx.z, (_Float16)vx.w};
        float4 vw = *(const float4*)(wo + (size_t)(bx * 128 + row) * RDIM + schunk * 4);
        *(v4h*)(Wh + row * 72 + schunk * 4) =
            (v4h){(_Float16)vw.x, (_Float16)vw.y, (_Float16)vw.z, (_Float16)vw.w};
    }
    __syncthreads();

    v4f facc[4][4];
#pragma unroll
    for (int i = 0; i < 4; ++i)
#pragma unroll
        for (int j = 0; j < 4; ++j) facc[i][j] = (v4f){0.f, 0.f, 0.f, 0.f};

    const int lkh = (lane >> 4) * 8;
#pragma unroll
    for (int ks = 0; ks < 2; ++ks) {
        v8h ah[4], bh[4];
#pragma unroll
        for (int i = 0; i < 4; ++i)
            ah[i] = *(const v8h*)(Xh + (wm * 64 + i * 16 + lr) * 72 + ks * 32 + lkh);
#pragma unroll
        for (int j = 0; j < 4; ++j)
            bh[j] = *(const v8h*)(Wh + (wn * 64 + j * 16 + lr) * 72 + ks * 32 + lkh);
#pragma unroll
        for (int i = 0; i < 4; ++i)
#pragma unroll
            for (int j = 0; j < 4; ++j)
                facc[i][j] = __builtin_amdgcn_mfma_f32_16x16x32_f16(ah[i], bh[j], facc[i][j], 0, 0, 0);
    }

#pragma unroll
    for (int i = 0; i < 4; ++i) {
        int row0 = wm * 64 + i * 16 + (lane >> 4) * 4;
#pragma unroll
        for (int j = 0; j < 4; ++j) {
            int col = wn * 64 + j * 16 + lr;
            float sw = ws_s[col];
            float bz = bs_s[col];
#pragma unroll
            for (int r = 0; r < 4; ++r) {
                int row = row0 + r;
                float v = (float)acc[i][j][r] * xs_s[row] * sw + bz + facc[i][j][r];
                out[(size_t)(by * 128 + row) * NDIM + (bx * 128 + col)] = v;
            }
        }
    }
}

extern "C" void kernel_launch(void* const* d_in, const int* in_sizes, int n_in,
                              void* d_out, int out_size, void* d_ws, size_t ws_size,
                              hipStream_t stream) {
    const int*   xq   = (const int*)d_in[0];
    const float* xsc  = (const float*)d_in[1];
    const int*   wq   = (const int*)d_in[2];
    const float* wsc  = (const float*)d_in[3];
    const float* bias = (const float*)d_in[4];
    const float* xr   = (const float*)d_in[5];
    const float* wo   = (const float*)d_in[6];
    float* out = (float*)d_out;

    const size_t X8 = (size_t)MDIM * KDIM;
    const size_t W8 = (size_t)NDIM * KDIM;

    if (ws_size >= X8 + W8) {
        char* x8 = (char*)d_ws;
        char* w8 = x8 + X8;
        repack_int4<<<2048, 256, 0, stream>>>(xq, wq, x8, w8);
        w4a4_big<<<(MDIM / 256) * (NDIM / 256), 256, 0, stream>>>(
            x8, w8, xsc, wsc, bias, xr, wo, out);
    } else {
        w4a4_fused<<<(MDIM / 128) * (NDIM / 128), 256, 0, stream>>>(
            xq, xsc, wq, wsc, bias, xr, wo, out);
    }
}

// Round 10
// 177.230 us; speedup vs baseline: 1.2267x; 1.1499x over previous
//
#include <hip/hip_runtime.h>
#include <hip/hip_fp16.h>

typedef int      v4i  __attribute__((ext_vector_type(4)));
typedef int      v2i  __attribute__((ext_vector_type(2)));
typedef int      v16i __attribute__((ext_vector_type(16)));
typedef float    v4f  __attribute__((ext_vector_type(4)));
typedef float    v16f __attribute__((ext_vector_type(16)));
typedef _Float16 v8h  __attribute__((ext_vector_type(8)));
typedef _Float16 v4h  __attribute__((ext_vector_type(4)));

#define MDIM 8192
#define NDIM 4096
#define KDIM 4096
#define RDIM 64
#define KW   (KDIM / 2)
#define NT   (KDIM / 128)        // 32 K-tiles of BK=128 int8

typedef const __attribute__((address_space(1))) char* gas_ptr;
typedef __attribute__((address_space(3))) char*       las_ptr;

__device__ __forceinline__ void unpack_w(v4i w, int& lo8, int& hi8) {
    unsigned p01 = __builtin_amdgcn_perm((unsigned)w.y, (unsigned)w.x, 0x0C0C0400u);
    unsigned p23 = __builtin_amdgcn_perm((unsigned)w.w, (unsigned)w.z, 0x0C0C0400u);
    unsigned b4  = __builtin_amdgcn_perm(p23, p01, 0x05040100u);
    unsigned lo = b4 & 0x0F0F0F0Fu;
    unsigned hi = (b4 >> 4) & 0x0F0F0F0Fu;
    lo8 = (int)(((lo ^ 0x08080808u) + 0x78787878u) ^ 0x80808080u);
    hi8 = (int)(((hi ^ 0x08080808u) + 0x78787878u) ^ 0x80808080u);
}

// ---------------- kernel 1: repack packed-int32 nibbles -> dense int8 -------
__global__ __launch_bounds__(256)
void repack_int4(const int* __restrict__ xq, const int* __restrict__ wq,
                 char* __restrict__ x8, char* __restrict__ w8)
{
    const size_t XCH = (size_t)MDIM * KW / 4;
    const size_t TCH = XCH + (size_t)NDIM * KW / 4;
    size_t stride = (size_t)gridDim.x * blockDim.x;
    for (size_t i = (size_t)blockIdx.x * blockDim.x + threadIdx.x; i < TCH; i += stride) {
        const int* src;
        char* dst;
        if (i < XCH) { src = xq + i * 4; dst = x8 + i * 8; }
        else { size_t j = i - XCH; src = wq + j * 4; dst = w8 + j * 8; }
        v4i w = *(const v4i*)src;
        int lo8, hi8;
        unpack_w(w, lo8, hi8);
        *(v2i*)dst = (v2i){lo8, hi8};
    }
}

// -------- kernel 2: 256x256 merged-4-phase int8 GEMM, 32x32x32 MFMA --------
// r5 skeleton (proven 147us/42.8%): 8 waves (2Mx4N), wave tile 128x64 as a
// 4x2 grid of 32x32 tiles; BK=128/2 sub-buffers; 1 barrier + vmcnt(4)/phase;
// SGB weave; read-ahead ping-pong frags. Only the MFMA shape changed:
// i32_32x32x32_i8 = +11.7% ubench rate, half the instruction count.
__device__ __forceinline__ void stage2(const char* g, char* l, int kt, int ks) {
    const char* s = g + kt * 128 + ks * 64;
    __builtin_amdgcn_global_load_lds((gas_ptr)(const void*)s,
                                     (las_ptr)(void*)l, 16, 0, 0);
    __builtin_amdgcn_global_load_lds((gas_ptr)(const void*)(s + (size_t)128 * KDIM),
                                     (las_ptr)(void*)(l + 8192), 16, 0, 0);
}

#define BAR asm volatile("s_barrier" ::: "memory")
#define VM4 asm volatile("s_waitcnt vmcnt(4)" ::: "memory")
#define SGB(m, n) __builtin_amdgcn_sched_group_barrier(m, n, 0)

// weave: 12 DS_READ (0x100) + 4 VMEM (0x30) laced through 16 MFMA (0x8)
#define SGBSEQ do {                                                            \
    SGB(0x100, 2); SGB(0x8, 2); SGB(0x100, 2); SGB(0x8, 2);                    \
    SGB(0x100, 2); SGB(0x8, 2); SGB(0x100, 2); SGB(0x8, 2);                    \
    SGB(0x100, 2); SGB(0x8, 2); SGB(0x100, 2); SGB(0x8, 2);                    \
    SGB(0x30, 2);  SGB(0x8, 2); SGB(0x30, 2);  SGB(0x8, 2);                    \
} while (0)

// read-ahead: 4 A-tiles x 2 ksteps + 2 B-tiles x 2 ksteps from [PAR][KS]
#define READ_AB(DA, DB, PAR, KS_) do {                                         \
    const char* Ab_ = (const char*)Asub[PAR][KS_];                             \
    const char* Bb_ = (const char*)Bsub[PAR][KS_];                             \
    _Pragma("unroll")                                                          \
    for (int ii = 0; ii < 4; ++ii) {                                           \
        DA[ii][0] = *(const v4i*)(Ab_ + aoff + ii * 2048);                     \
        DA[ii][1] = *(const v4i*)(Ab_ + (aoff ^ 32) + ii * 2048);              \
    }                                                                          \
    _Pragma("unroll")                                                          \
    for (int jj = 0; jj < 2; ++jj) {                                           \
        DB[jj][0] = *(const v4i*)(Bb_ + boff + jj * 2048);                     \
        DB[jj][1] = *(const v4i*)(Bb_ + (boff ^ 32) + jj * 2048);              \
    }                                                                          \
} while (0)

#define MMA16(AS, BS)                                                          \
    _Pragma("unroll")                                                          \
    for (int ks_ = 0; ks_ < 2; ++ks_)                                          \
        _Pragma("unroll")                                                      \
        for (int ii = 0; ii < 4; ++ii)                                         \
            _Pragma("unroll")                                                  \
            for (int jj = 0; jj < 2; ++jj)                                     \
                acc[ii][jj] = __builtin_amdgcn_mfma_i32_32x32x32_i8(           \
                    AS[ii][ks_], BS[jj][ks_], acc[ii][jj], 0, 0, 0)

// CUR set computed; NXT set read-ahead from [NPAR][NKS]; stage [SPAR][SKS]<-SKT
#define QPHASE(CA, CB, NA, NB, NPAR, NKS, SPAR, SKS, SKT) do {                 \
    READ_AB(NA, NB, NPAR, NKS);                                                \
    stage2(gA, &Asub[SPAR][SKS][ldsW], SKT, SKS);                              \
    stage2(gB, &Bsub[SPAR][SKS][ldsW], SKT, SKS);                              \
    MMA16(CA, CB);                                                             \
    SGBSEQ;                                                                    \
    VM4; BAR;                                                                  \
} while (0)

__global__ __launch_bounds__(512, 2)
void w4a4_g32(const char* __restrict__ x8, const char* __restrict__ w8,
              const float* __restrict__ xsc, const float* __restrict__ wsc,
              const float* __restrict__ bias, const float* __restrict__ xr,
              const float* __restrict__ wo, float* __restrict__ out)
{
    // [parity][k-half][256 rows x 64B], swizzled: byte c of row r holds
    // global col c ^ (((r>>1)&3)<<4). 128 KiB total.
    __shared__ __align__(16) char Asub[2][2][16384];
    __shared__ __align__(16) char Bsub[2][2][16384];
    __shared__ float xs_s[256];
    __shared__ float ws_s[256];
    __shared__ float bs_s[256];

    const int tid  = threadIdx.x;
    const int lane = tid & 63;
    const int wid  = tid >> 6;     // 0..7
    const int wm   = wid >> 2;     // M half (0..1)
    const int wn   = wid & 3;      // N quarter (0..3)

    // bijective XCD swizzle: 512 blocks = 8 XCDs x 64
    const int s  = (blockIdx.x & 7) * 64 + (blockIdx.x >> 3);
    const int by = s >> 4;         // 0..31
    const int bxn = s & 15;        // 0..15

    if (tid < 256) {
        xs_s[tid] = xsc[by * 256 + tid];
    } else {
        int n = tid - 256;
        ws_s[n] = wsc[bxn * 256 + n];
        bs_s[n] = bias[bxn * 256 + n];
    }

    // staging geometry: lane covers 16B of row (wid*16 + lane/4), pre-swizzled col
    const int srow = wid * 16 + (lane >> 2);
    const int scol = ((lane & 3) * 16) ^ (((lane >> 3) & 3) << 4);
    const char* gA = x8 + (size_t)(by * 256 + srow) * KDIM + scol;
    const char* gB = w8 + (size_t)(bxn * 256 + srow) * KDIM + scol;
    const int ldsW = wid * 1024;

    // 32x32 fragment geometry: A row = lane&31, k-byte = (lane>>5)*16;
    // swizzle XOR ((l31>>1)&3)<<4 is lane-constant; kstep flips bit 5 (XOR).
    const int l31 = lane & 31;
    const int kh  = lane >> 5;     // 0..1
    const int cks = (kh << 4) ^ (((l31 >> 1) & 3) << 4);
    const int aoff = (wm * 128 + l31) * 64 + cks;
    const int boff = (wn * 64  + l31) * 64 + cks;

    v16i acc[4][2];
#pragma unroll
    for (int i = 0; i < 4; ++i)
#pragma unroll
        for (int j = 0; j < 2; ++j)
#pragma unroll
            for (int r = 0; r < 16; ++r) acc[i][j][r] = 0;

    // prologue: stage [0][0]@kt0, [0][1]@kt0, [1][0]@kt1 (12 loads/wave)
    stage2(gA, &Asub[0][0][ldsW], 0, 0);
    stage2(gB, &Bsub[0][0][ldsW], 0, 0);
    stage2(gA, &Asub[0][1][ldsW], 0, 1);
    stage2(gB, &Bsub[0][1][ldsW], 0, 1);
    stage2(gA, &Asub[1][0][ldsW], 1, 0);
    stage2(gB, &Bsub[1][0][ldsW], 1, 0);
    VM4;                                   // certify [0][0] + [0][1]
    BAR;

    // ping-pong fragment sets; read-ahead by exactly one phase
    v4i a0[4][2], b0[2][2], a1[4][2], b1[2][2];
    READ_AB(a0, b0, 0, 0);

    // Ledger identical to r5 (4 loads/phase/wave): stage at Qi is ds_read at
    // Qi+2; VM4 at phase end certifies through loads staged 2 phases earlier.
    for (int it = 0; it < NT / 2; ++it) {
        const int kt1 = 2 * it + 1;
        const int kt2 = (2 * it + 2 < NT) ? 2 * it + 2 : NT - 1;
        const int kt3 = (2 * it + 3 < NT) ? 2 * it + 3 : NT - 1;
        QPHASE(a0, b0, a1, b1, 0, 1, 1, 1, kt1);
        QPHASE(a1, b1, a0, b0, 1, 0, 0, 0, kt2);
        QPHASE(a0, b0, a1, b1, 1, 1, 0, 1, kt2);
        QPHASE(a1, b1, a0, b0, 0, 0, 1, 0, kt3);
    }

    // drain DMAs before overwriting LDS with the f16 outlier tiles
    asm volatile("s_waitcnt vmcnt(0)" ::: "memory");
    BAR;

    // ---- rank-64 outlier staging: f16 [256][64] (128B rows), XOR-swizzled
    // byte ^= ((row&7)<<4). Xh reuses Asub (32K), Wh reuses Bsub.
    char* Xh = (char*)&Asub[0][0][0];
    char* Wh = (char*)&Bsub[0][0][0];
    {
        const int rr = tid >> 3;          // 0..63
        const int cb = (tid & 7) * 16;    // byte col within 128B row
#pragma unroll
        for (int p = 0; p < 4; ++p) {
            const int row = p * 64 + rr;
            const int sw = cb ^ ((row & 7) << 4);
            v4f x0 = *(const v4f*)(xr + (size_t)(by * 256 + row) * RDIM + (cb >> 1));
            v4f x1 = *(const v4f*)(xr + (size_t)(by * 256 + row) * RDIM + (cb >> 1) + 4);
            v8h hx = {(_Float16)x0[0], (_Float16)x0[1], (_Float16)x0[2], (_Float16)x0[3],
                      (_Float16)x1[0], (_Float16)x1[1], (_Float16)x1[2], (_Float16)x1[3]};
            *(v8h*)(Xh + (size_t)row * 128 + sw) = hx;
            v4f w0 = *(const v4f*)(wo + (size_t)(bxn * 256 + row) * RDIM + (cb >> 1));
            v4f w1 = *(const v4f*)(wo + (size_t)(bxn * 256 + row) * RDIM + (cb >> 1) + 4);
            v8h hw = {(_Float16)w0[0], (_Float16)w0[1], (_Float16)w0[2], (_Float16)w0[3],
                      (_Float16)w1[0], (_Float16)w1[1], (_Float16)w1[2], (_Float16)w1[3]};
            *(v8h*)(Wh + (size_t)row * 128 + sw) = hw;
        }
    }

    // dequant in place (int acc -> f32 bits); 32x32 C layout:
    // col = l31, row_in_tile = (r&3) + 8*(r>>2) + 4*kh
#pragma unroll
    for (int i = 0; i < 4; ++i) {
        const int r0 = wm * 128 + i * 32 + kh * 4;
#pragma unroll
        for (int j = 0; j < 2; ++j) {
            const int col = wn * 64 + j * 32 + l31;
            const float sw = ws_s[col];
            const float bz = bs_s[col];
            v16f f;
#pragma unroll
            for (int q = 0; q < 4; ++q) {
                const v4f xs4 = *(const v4f*)&xs_s[r0 + q * 8];
#pragma unroll
                for (int r = 0; r < 4; ++r)
                    f[q * 4 + r] = (float)acc[i][j][q * 4 + r] * xs4[r] * sw + bz;
            }
            acc[i][j] = __builtin_bit_cast(v16i, f);
        }
    }
    __syncthreads();

    // rank-64 outlier: f32_32x32x16_f16, 4 ksteps over R=64, same C layout
    const int obsw = (kh << 4) ^ ((l31 & 7) << 4);   // lane-constant byte base
#pragma unroll
    for (int ks = 0; ks < 4; ++ks) {
        v8h ah[4], bh[2];
#pragma unroll
        for (int i = 0; i < 4; ++i) {
            const int row = wm * 128 + i * 32 + l31;
            ah[i] = *(const v8h*)(Xh + (size_t)row * 128 + (obsw ^ (ks << 5)));
        }
#pragma unroll
        for (int j = 0; j < 2; ++j) {
            const int row = wn * 64 + j * 32 + l31;
            bh[j] = *(const v8h*)(Wh + (size_t)row * 128 + (obsw ^ (ks << 5)));
        }
#pragma unroll
        for (int i = 0; i < 4; ++i)
#pragma unroll
            for (int j = 0; j < 2; ++j) {
                v16f c = __builtin_bit_cast(v16f, acc[i][j]);
                c = __builtin_amdgcn_mfma_f32_32x32x16_f16(ah[i], bh[j], c, 0, 0, 0);
                acc[i][j] = __builtin_bit_cast(v16i, c);
            }
    }

    // ---- store (32x32 C layout) ----
    const int colb = bxn * 256 + wn * 64 + l31;
    const int rowb = by * 256 + wm * 128 + kh * 4;
#pragma unroll
    for (int i = 0; i < 4; ++i)
#pragma unroll
        for (int j = 0; j < 2; ++j) {
            v16f f = __builtin_bit_cast(v16f, acc[i][j]);
            const int col = colb + j * 32;
#pragma unroll
            for (int q = 0; q < 4; ++q) {
                const int row = rowb + i * 32 + q * 8;
#pragma unroll
                for (int r = 0; r < 4; ++r)
                    out[(size_t)(row + r) * NDIM + col] = f[q * 4 + r];
            }
        }
}

// ---------------- fallback: fused single-kernel path (ws too small) --------
__global__ __launch_bounds__(256, 2)
void w4a4_fused(const int* __restrict__ xq, const float* __restrict__ xsc,
                const int* __restrict__ wq, const float* __restrict__ wsc,
                const float* __restrict__ bias, const float* __restrict__ xr,
                const float* __restrict__ wo, float* __restrict__ out)
{
    __shared__ __align__(16) char As[128 * 144];
    __shared__ __align__(16) char Bs[128 * 144];
    __shared__ float xs_s[128];
    __shared__ float ws_s[128];
    __shared__ float bs_s[128];

    const int tid  = threadIdx.x;
    const int lane = tid & 63;
    const int wid  = tid >> 6;
    const int wm   = wid >> 1;
    const int wn   = wid & 1;
    const int bx   = blockIdx.x % (NDIM / 128);
    const int by   = blockIdx.x / (NDIM / 128);

    const int srow   = tid >> 4;
    const int schunk = tid & 15;

    if (tid < 128) {
        xs_s[tid] = xsc[by * 128 + tid];
    } else {
        int n = tid - 128;
        ws_s[n] = wsc[bx * 128 + n];
        bs_s[n] = bias[bx * 128 + n];
    }

    const int* gA = xq + (size_t)(by * 128 + srow) * KW + schunk * 4;
    const int* gB = wq + (size_t)(bx * 128 + srow) * KW + schunk * 4;
    char* lA = As + srow * 144 + schunk * 8;
    char* lB = Bs + srow * 144 + schunk * 8;

    v4i acc[4][4];
#pragma unroll
    for (int i = 0; i < 4; ++i)
#pragma unroll
        for (int j = 0; j < 4; ++j) acc[i][j] = (v4i){0, 0, 0, 0};

    const int lr = lane & 15;
    const int lkb = (lane >> 4) * 16;

    for (int kt = 0; kt < KDIM / 128; ++kt) {
#pragma unroll
        for (int p = 0; p < 8; ++p) {
            v4i w = *(const v4i*)(gA + (size_t)p * 16 * KW + kt * 64);
            int lo8, hi8;
            unpack_w(w, lo8, hi8);
            *(v2i*)(lA + p * 16 * 144) = (v2i){lo8, hi8};
        }
#pragma unroll
        for (int p = 0; p < 8; ++p) {
            v4i w = *(const v4i*)(gB + (size_t)p * 16 * KW + kt * 64);
            int lo8, hi8;
            unpack_w(w, lo8, hi8);
            *(v2i*)(lB + p * 16 * 144) = (v2i){lo8, hi8};
        }
        __syncthreads();
#pragma unroll
        for (int ks = 0; ks < 2; ++ks) {
            v4i av[4], bv[4];
#pragma unroll
            for (int i = 0; i < 4; ++i)
                av[i] = *(const v4i*)(As + (wm * 64 + i * 16 + lr) * 144 + ks * 64 + lkb);
#pragma unroll
            for (int j = 0; j < 4; ++j)
                bv[j] = *(const v4i*)(Bs + (wn * 64 + j * 16 + lr) * 144 + ks * 64 + lkb);
#pragma unroll
            for (int i = 0; i < 4; ++i)
#pragma unroll
                for (int j = 0; j < 4; ++j)
                    acc[i][j] = __builtin_amdgcn_mfma_i32_16x16x64_i8(av[i], bv[j], acc[i][j], 0, 0, 0);
        }
        __syncthreads();
    }

    _Float16* Xh = (_Float16*)As;
    _Float16* Wh = (_Float16*)Bs;
#pragma unroll
    for (int p = 0; p < 8; ++p) {
        int row = p * 16 + srow;
        float4 vx = *(const float4*)(xr + (size_t)(by * 128 + row) * RDIM + schunk * 4);
        *(v4h*)(Xh + row * 72 + schunk * 4) =
            (v4h){(_Float16)vx.x, (_Float16)vx.y, (_Float16)vx.z, (_Float16)vx.w};
        float4 vw = *(const float4*)(wo + (size_t)(bx * 128 + row) * RDIM + schunk * 4);
        *(v4h*)(Wh + row * 72 + schunk * 4) =
            (v4h){(_Float16)vw.x, (_Float16)vw.y, (_Float16)vw.z, (_Float16)vw.w};
    }
    __syncthreads();

    v4f facc[4][4];
#pragma unroll
    for (int i = 0; i < 4; ++i)
#pragma unroll
        for (int j = 0; j < 4; ++j) facc[i][j] = (v4f){0.f, 0.f, 0.f, 0.f};

    const int lkh = (lane >> 4) * 8;
#pragma unroll
    for (int ks = 0; ks < 2; ++ks) {
        v8h ah[4], bh[4];
#pragma unroll
        for (int i = 0; i < 4; ++i)
            ah[i] = *(const v8h*)(Xh + (wm * 64 + i * 16 + lr) * 72 + ks * 32 + lkh);
#pragma unroll
        for (int j = 0; j < 4; ++j)
            bh[j] = *(const v8h*)(Wh + (wn * 64 + j * 16 + lr) * 72 + ks * 32 + lkh);
#pragma unroll
        for (int i = 0; i < 4; ++i)
#pragma unroll
            for (int j = 0; j < 4; ++j)
                facc[i][j] = __builtin_amdgcn_mfma_f32_16x16x32_f16(ah[i], bh[j], facc[i][j], 0, 0, 0);
    }

#pragma unroll
    for (int i = 0; i < 4; ++i) {
        int row0 = wm * 64 + i * 16 + (lane >> 4) * 4;
#pragma unroll
        for (int j = 0; j < 4; ++j) {
            int col = wn * 64 + j * 16 + lr;
            float sw = ws_s[col];
            float bz = bs_s[col];
#pragma unroll
            for (int r = 0; r < 4; ++r) {
                int row = row0 + r;
                float v = (float)acc[i][j][r] * xs_s[row] * sw + bz + facc[i][j][r];
                out[(size_t)(by * 128 + row) * NDIM + (bx * 128 + col)] = v;
            }
        }
    }
}

extern "C" void kernel_launch(void* const* d_in, const int* in_sizes, int n_in,
                              void* d_out, int out_size, void* d_ws, size_t ws_size,
                              hipStream_t stream) {
    const int*   xq   = (const int*)d_in[0];
    const float* xsc  = (const float*)d_in[1];
    const int*   wq   = (const int*)d_in[2];
    const float* wsc  = (const float*)d_in[3];
    const float* bias = (const float*)d_in[4];
    const float* xr   = (const float*)d_in[5];
    const float* wo   = (const float*)d_in[6];
    float* out = (float*)d_out;

    const size_t X8 = (size_t)MDIM * KDIM;
    const size_t W8 = (size_t)NDIM * KDIM;

    if (ws_size >= X8 + W8) {
        char* x8 = (char*)d_ws;
        char* w8 = x8 + X8;
        repack_int4<<<2048, 256, 0, stream>>>(xq, wq, x8, w8);
        w4a4_g32<<<(MDIM / 256) * (NDIM / 256), 512, 0, stream>>>(
            x8, w8, xsc, wsc, bias, xr, wo, out);
    } else {
        w4a4_fused<<<(MDIM / 128) * (NDIM / 128), 256, 0, stream>>>(
            xq, xsc, wq, wsc, bias, xr, wo, out);
    }
}